// Round 5
// baseline (386.107 us; speedup 1.0000x reference)
//
#include <hip/hip_runtime.h>
#include <hip/hip_bf16.h>

typedef unsigned int uint;
typedef unsigned short ushort;
typedef __attribute__((ext_vector_type(8))) short bf16x8;
typedef __attribute__((ext_vector_type(4))) float f32x4;
typedef __attribute__((ext_vector_type(2))) float f32x2;
typedef __attribute__((ext_vector_type(4))) int i32x4;
typedef __attribute__((ext_vector_type(4))) float f32x4v;

// ---- bf16 helpers (f32 accumulate everywhere; bf16 only for stored tensors) ----
__device__ __forceinline__ float2 bf2f2(uint p) {
    float2 r;
    r.x = __uint_as_float(p << 16);
    r.y = __uint_as_float(p & 0xffff0000u);
    return r;
}
__device__ __forceinline__ ushort f2bf(float f) {
    uint u = __float_as_uint(f);
    return (ushort)((u + 0x7fffu + ((u >> 16) & 1u)) >> 16);
}
__device__ __forceinline__ uint packbf(float a, float b) {
    return (uint)f2bf(a) | ((uint)f2bf(b) << 16);
}

// ---------------- CSR build ----------------
__global__ void k_hist(const int* __restrict__ dst, int* __restrict__ cnt, int E) {
    int e = (blockIdx.x * 256 + threadIdx.x) * 4;
    if (e + 3 < E) {
        i32x4 d = __builtin_nontemporal_load(reinterpret_cast<const i32x4*>(&dst[e]));
        atomicAdd(&cnt[d.x], 1);
        atomicAdd(&cnt[d.y], 1);
        atomicAdd(&cnt[d.z], 1);
        atomicAdd(&cnt[d.w], 1);
    } else {
        for (int q = 0; q < 4; ++q)
            if (e + q < E) atomicAdd(&cnt[dst[e + q]], 1);
    }
}

__device__ __forceinline__ int block_excl_scan(int tsum, int tid, int* wtot) {
    int lane = tid & 63, w = tid >> 6;
    int incl = tsum;
    for (int off = 1; off < 64; off <<= 1) {
        int t = __shfl_up(incl, off);
        if (lane >= off) incl += t;
    }
    if (lane == 63) wtot[w] = incl;
    __syncthreads();
    int woff = 0;
    if (w > 0) woff = wtot[0];
    if (w > 1) woff += wtot[1];
    if (w > 2) woff += wtot[2];
    return woff + incl - tsum;
}

__global__ __launch_bounds__(256)
void k_scanA(const int* __restrict__ cnt, int* __restrict__ btot, int N) {
    __shared__ int wtot[4];
    int tid = threadIdx.x;
    int base = blockIdx.x * 1024 + tid * 4;
    int s = 0;
    if (base + 3 < N) {
        int4 v = *reinterpret_cast<const int4*>(&cnt[base]);
        s = v.x + v.y + v.z + v.w;
    } else {
#pragma unroll
        for (int q = 0; q < 4; ++q) { int i = base + q; if (i < N) s += cnt[i]; }
    }
    int lane = tid & 63, w = tid >> 6;
    for (int off = 32; off; off >>= 1) s += __shfl_down(s, off);
    if (lane == 0) wtot[w] = s;
    __syncthreads();
    if (tid == 0) btot[blockIdx.x] = wtot[0] + wtot[1] + wtot[2] + wtot[3];
}

__global__ __launch_bounds__(256)
void k_scanB(const int* __restrict__ btot, int* __restrict__ boff,
             int* __restrict__ rowptr, int NB, int N, int E) {
    __shared__ int wtot[4];
    int tid = threadIdx.x;
    int v = (tid < NB) ? btot[tid] : 0;
    int ex = block_excl_scan(v, tid, wtot);
    if (tid < NB) boff[tid] = ex;
    if (tid == 0) rowptr[N] = E;
}

// re-scan chunks + write rowptr/cursor; fused dinv (pre-scan cnt values ARE degrees)
__global__ __launch_bounds__(256)
void k_scanC(int* __restrict__ cnt, const int* __restrict__ boff,
             int* __restrict__ rowptr, float* __restrict__ dinv, int N) {
    __shared__ int wtot[4];
    int tid = threadIdx.x;
    int base = blockIdx.x * 1024 + tid * 4;
    int v0 = 0, v1 = 0, v2 = 0, v3 = 0;
    if (base + 3 < N) {
        int4 v = *reinterpret_cast<const int4*>(&cnt[base]);
        v0 = v.x; v1 = v.y; v2 = v.z; v3 = v.w;
    } else {
        if (base + 0 < N) v0 = cnt[base + 0];
        if (base + 1 < N) v1 = cnt[base + 1];
        if (base + 2 < N) v2 = cnt[base + 2];
        if (base + 3 < N) v3 = cnt[base + 3];
    }
    int tsum = v0 + v1 + v2 + v3;
    int ex = block_excl_scan(tsum, tid, wtot) + boff[blockIdx.x];
    int r0 = ex, r1 = ex + v0, r2 = r1 + v1, r3 = r2 + v2;
    if (base + 0 < N) { rowptr[base + 0] = r0; cnt[base + 0] = r0; dinv[base + 0] = rsqrtf((float)v0 + 1.0f); }
    if (base + 1 < N) { rowptr[base + 1] = r1; cnt[base + 1] = r1; dinv[base + 1] = rsqrtf((float)v1 + 1.0f); }
    if (base + 2 < N) { rowptr[base + 2] = r2; cnt[base + 2] = r2; dinv[base + 2] = rsqrtf((float)v2 + 1.0f); }
    if (base + 3 < N) { rowptr[base + 3] = r3; cnt[base + 3] = r3; dinv[base + 3] = rsqrtf((float)v3 + 1.0f); }
}

template<typename CT>
__global__ void k_fill(const int* __restrict__ src, const int* __restrict__ dst,
                       int* __restrict__ cursor, CT* __restrict__ col, int E) {
    int e = (blockIdx.x * 256 + threadIdx.x) * 4;
    if (e + 3 < E) {
        i32x4 s = __builtin_nontemporal_load(reinterpret_cast<const i32x4*>(&src[e]));
        i32x4 d = __builtin_nontemporal_load(reinterpret_cast<const i32x4*>(&dst[e]));
        col[atomicAdd(&cursor[d.x], 1)] = (CT)s.x;
        col[atomicAdd(&cursor[d.y], 1)] = (CT)s.y;
        col[atomicAdd(&cursor[d.z], 1)] = (CT)s.z;
        col[atomicAdd(&cursor[d.w], 1)] = (CT)s.w;
    } else {
        for (int q = 0; q < 4; ++q)
            if (e + q < E) col[atomicAdd(&cursor[dst[e + q]], 1)] = (CT)src[e + q];
    }
}

// pack h0 = [x | s] as bf16, row stride 128
__global__ void k_pack(const float* __restrict__ xi, const float* __restrict__ si,
                       ushort* __restrict__ h, int n4) {   // n4 = N*16
    int i = blockIdx.x * 256 + threadIdx.x;
    if (i >= n4) return;
    int row = i >> 4, c4 = i & 15;
    f32x4v xv = __builtin_nontemporal_load(reinterpret_cast<const f32x4v*>(&xi[i * 4]));
    f32x4v sv = __builtin_nontemporal_load(reinterpret_cast<const f32x4v*>(&si[i * 4]));
    ushort4 xo, so;
    xo.x = f2bf(xv.x); xo.y = f2bf(xv.y); xo.z = f2bf(xv.z); xo.w = f2bf(xv.w);
    so.x = f2bf(sv.x); so.y = f2bf(sv.y); so.z = f2bf(sv.z); so.w = f2bf(sv.w);
    *reinterpret_cast<ushort4*>(&h[(size_t)row * 128 + c4 * 4]) = xo;
    *reinterpret_cast<ushort4*>(&h[(size_t)row * 128 + 64 + c4 * 4]) = so;
}

// weights: transpose + convert to bf16 once. WT[j][k] = W[k][j]  (Wh stays f32, used by k_out)
__global__ void k_prep(const float* __restrict__ W1, const float* __restrict__ W2,
                       const float* __restrict__ Wg,
                       ushort* __restrict__ W1T, ushort* __restrict__ W2T,
                       ushort* __restrict__ WgT, int L) {
    int i = blockIdx.x * 256 + threadIdx.x;
    int n1 = L * 8192, n2 = L * 4096;
    if (i < n1) {
        int li = i >> 13, r = i & 8191, j = r >> 7, kk = r & 127;
        W1T[i] = f2bf(W1[(size_t)li * 8192 + kk * 64 + j]);
    } else if (i < n1 + n2) {
        int t = i - n1; int li = t >> 12, r = t & 4095, j = r >> 6, kk = r & 63;
        W2T[t] = f2bf(W2[(size_t)li * 4096 + kk * 64 + j]);
    } else if (i < n1 + 2 * n2) {
        int t = i - n1 - n2; int li = t >> 12, r = t & 4095, j = r >> 6, kk = r & 63;
        WgT[t] = f2bf(Wg[(size_t)li * 4096 + kk * 64 + j]);
    }
}

// ---------------- fused gather + MFMA layer ----------------
// 4 waves/block, each wave owns 16 rows end-to-end: gather (GIN sum + dinv-weighted s sum)
// into per-wave XOR-swizzled LDS tiles, then stage1/2/3 MFMA. No __syncthreads at all:
// every LDS dependency is intra-wave (compiler lgkmcnt waits handle it), so waves never
// couple and gather load-imbalance in one wave doesn't stall the others.
template<typename CT>
__global__ __launch_bounds__(256)
void k_fused(const uint* __restrict__ hprev,  // [N][64] uints (=128 bf16 feats)
             const float* __restrict__ dinv,
             const int* __restrict__ rowptr, const CT* __restrict__ col,
             const ushort* __restrict__ W1T,  // [64][128] bf16
             const ushort* __restrict__ W2T,  // [64][64]
             const ushort* __restrict__ WgT,  // [64][64]
             const float* __restrict__ bg,
             ushort* __restrict__ hout, int N) {
    __shared__ uint gT[4][1024];   // per-wave 16 rows x 64 uints (128 bf16), swizzled
    __shared__ uint tbT[4][512];   // per-wave 16 rows x 32 uints (64 bf16),  swizzled
    __shared__ short sT[4][1024];  // per-wave 16x64 bf16 T-tile, swizzled
    int w = threadIdx.x >> 6, l = threadIdx.x & 63;
    int p = l >> 4, q16 = l & 15;
    int r0 = blockIdx.x * 64 + w * 16;
    uint* gw = gT[w];
    uint* tbw = tbT[w];
    short* sw = sT[w];

    // ---- gather phase: 16 rows sequentially, software-pipelined neighbor loop ----
    for (int rr = 0; rr < 16; ++rr) {
        int v = r0 + rr;
        float ax = 0.f, ay = 0.f, dx = 0.f, dy = 0.f;
        if (v < N) {
            float dv = dinv[v];
            float2 hv = bf2f2(hprev[(size_t)v * 64 + l]);
            ax = hv.x; ay = hv.y;
            dx = dv * hv.x; dy = dv * hv.y;
            int k = rowptr[v], end = rowptr[v + 1];
            int u0 = 0, u1 = 0, u2 = 0, u3 = 0;
            if (k + 3 < end) { u0 = col[k]; u1 = col[k + 1]; u2 = col[k + 2]; u3 = col[k + 3]; }
            for (; k + 7 < end; k += 4) {
                int n0 = col[k + 4], n1 = col[k + 5], n2 = col[k + 6], n3 = col[k + 7];
                float d0 = dinv[u0], d1 = dinv[u1], d2 = dinv[u2], d3 = dinv[u3];
                float2 a = bf2f2(hprev[(size_t)u0 * 64 + l]);
                float2 b = bf2f2(hprev[(size_t)u1 * 64 + l]);
                float2 c = bf2f2(hprev[(size_t)u2 * 64 + l]);
                float2 e = bf2f2(hprev[(size_t)u3 * 64 + l]);
                ax += (a.x + b.x) + (c.x + e.x);
                ay += (a.y + b.y) + (c.y + e.y);
                dx = fmaf(d0, a.x, fmaf(d1, b.x, fmaf(d2, c.x, fmaf(d3, e.x, dx))));
                dy = fmaf(d0, a.y, fmaf(d1, b.y, fmaf(d2, c.y, fmaf(d3, e.y, dy))));
                u0 = n0; u1 = n1; u2 = n2; u3 = n3;
            }
            if (k + 3 < end) {
                float d0 = dinv[u0], d1 = dinv[u1], d2 = dinv[u2], d3 = dinv[u3];
                float2 a = bf2f2(hprev[(size_t)u0 * 64 + l]);
                float2 b = bf2f2(hprev[(size_t)u1 * 64 + l]);
                float2 c = bf2f2(hprev[(size_t)u2 * 64 + l]);
                float2 e = bf2f2(hprev[(size_t)u3 * 64 + l]);
                ax += (a.x + b.x) + (c.x + e.x);
                ay += (a.y + b.y) + (c.y + e.y);
                dx = fmaf(d0, a.x, fmaf(d1, b.x, fmaf(d2, c.x, fmaf(d3, e.x, dx))));
                dy = fmaf(d0, a.y, fmaf(d1, b.y, fmaf(d2, c.y, fmaf(d3, e.y, dy))));
                k += 4;
            }
            for (; k < end; ++k) {
                int u = col[k];
                float du = dinv[u];
                float2 a = bf2f2(hprev[(size_t)u * 64 + l]);
                ax += a.x; ay += a.y;
                dx = fmaf(du, a.x, dx);
                dy = fmaf(du, a.y, dy);
            }
            dx *= dv; dy *= dv;
        }
        gw[rr * 64 + (l ^ ((rr & 7) << 2))] = packbf(ax, ay);
        if (l >= 32) tbw[rr * 32 + ((l - 32) ^ ((rr & 7) << 2))] = packbf(dx, dy);
    }

    // ---- stage 1: T = g @ W1  (K=128) ----
    f32x4 acc1[4] = {};
#pragma unroll
    for (int kt = 0; kt < 4; ++kt) {
        bf16x8 a = *reinterpret_cast<const bf16x8*>(&gw[q16 * 64 + ((kt * 16 + p * 4) ^ ((q16 & 7) << 2))]);
#pragma unroll
        for (int jt = 0; jt < 4; ++jt) {
            bf16x8 b = *reinterpret_cast<const bf16x8*>(&W1T[(size_t)(jt * 16 + q16) * 128 + kt * 32 + p * 8]);
            acc1[jt] = __builtin_amdgcn_mfma_f32_16x16x32_bf16(a, b, acc1[jt], 0, 0, 0);
        }
    }
    // leaky + write T-tile to LDS (swizzle: short-index col ^ ((row&7)<<3))
#pragma unroll
    for (int jt = 0; jt < 4; ++jt) {
#pragma unroll
        for (int q = 0; q < 4; ++q) {
            float v = acc1[jt][q];
            v = v > 0.f ? v : 0.01f * v;
            int m = 4 * p + q;
            int c = jt * 16 + q16;
            sw[m * 64 + (c ^ ((m & 7) << 3))] = (short)f2bf(v);
        }
    }
    // ---- stage 2: x' = T @ W2 ; stage 3: s'pre = tb @ Wg  (K=64) ----
    f32x4 acc2[4] = {}, acc3[4] = {};
#pragma unroll
    for (int kt = 0; kt < 2; ++kt) {
        int koff = kt * 32 + p * 8;  // feature (short) offset
        bf16x8 at = *reinterpret_cast<const bf16x8*>(&sw[q16 * 64 + (koff ^ ((q16 & 7) << 3))]);
        bf16x8 av = *reinterpret_cast<const bf16x8*>(&tbw[q16 * 32 + ((kt * 16 + p * 4) ^ ((q16 & 7) << 2))]);
#pragma unroll
        for (int jt = 0; jt < 4; ++jt) {
            bf16x8 b2 = *reinterpret_cast<const bf16x8*>(&W2T[(size_t)(jt * 16 + q16) * 64 + koff]);
            bf16x8 b3 = *reinterpret_cast<const bf16x8*>(&WgT[(size_t)(jt * 16 + q16) * 64 + koff]);
            acc2[jt] = __builtin_amdgcn_mfma_f32_16x16x32_bf16(at, b2, acc2[jt], 0, 0, 0);
            acc3[jt] = __builtin_amdgcn_mfma_f32_16x16x32_bf16(av, b3, acc3[jt], 0, 0, 0);
        }
    }
    // ---- epilogue: h' = [x' | tanh(s'pre + bg)] ----
#pragma unroll
    for (int jt = 0; jt < 4; ++jt) {
        int c = jt * 16 + q16;
        float bgv = bg[c];
#pragma unroll
        for (int q = 0; q < 4; ++q) {
            int row = r0 + 4 * p + q;
            if (row < N) {
                hout[(size_t)row * 128 + c] = f2bf(acc2[jt][q]);
                hout[(size_t)row * 128 + 64 + c] = f2bf(tanhf(acc3[jt][q] + bgv));
            }
        }
    }
}

// ---------------- BatchNorm stats (final layer only) ----------------
__global__ __launch_bounds__(256)
void k_bnstats(const ushort* __restrict__ h, float* __restrict__ stats, int N) {
    __shared__ float ls[4][64], ls2[4][64];
    int w = threadIdx.x >> 6, j = threadIdx.x & 63;
    float s = 0.f, s2 = 0.f;
    for (int r = blockIdx.x * 4 + w; r < N; r += gridDim.x * 4) {
        float v = __uint_as_float((uint)h[(size_t)r * 128 + j] << 16);
        s += v; s2 += v * v;
    }
    ls[w][j] = s; ls2[w][j] = s2;
    __syncthreads();
    if (w == 0) {
        s = ls[0][j] + ls[1][j] + ls[2][j] + ls[3][j];
        s2 = ls2[0][j] + ls2[1][j] + ls2[2][j] + ls2[3][j];
        atomicAdd(&stats[j], s);
        atomicAdd(&stats[64 + j], s2);
    }
}

// ---------------- fused BN-apply + x_local write + per-graph pooled partials ----------------
__global__ __launch_bounds__(256)
void k_bnpool(const uint* __restrict__ h32, const float* __restrict__ stats,
              const float* __restrict__ gamma, const float* __restrict__ beta,
              const int* __restrict__ batch, float* __restrict__ xlocal,
              float* __restrict__ ph, int* __restrict__ pcnt, int N, int rpw) {
    int wg = blockIdx.x * 4 + (threadIdx.x >> 6);
    int l = threadIdx.x & 63;
    int r = wg * rpw;
    int rend = r + rpw; if (rend > N) rend = N;
    if (r >= rend) return;
    float invN = 1.0f / (float)N;
    bool isx = (l < 32);
    int f0 = 2 * l, f1 = 2 * l + 1;
    float mean0 = 0.f, mean1 = 0.f, inv0 = 1.f, inv1 = 1.f;
    float ga0 = 0.f, ga1 = 0.f, be0 = 0.f, be1 = 0.f;
    if (isx) {
        mean0 = stats[f0] * invN; mean1 = stats[f1] * invN;
        float v0 = stats[64 + f0] * invN - mean0 * mean0;
        float v1 = stats[64 + f1] * invN - mean1 * mean1;
        inv0 = rsqrtf(v0 + 1e-4f); inv1 = rsqrtf(v1 + 1e-4f);
        ga0 = gamma[f0]; ga1 = gamma[f1]; be0 = beta[f0]; be1 = beta[f1];
    }
    int cur = batch[r];
    float a0 = 0.f, a1 = 0.f; int cnt = 0;
    for (; r < rend; ++r) {
        int b = batch[r];
        if (b != cur) {
            atomicAdd(&ph[cur * 128 + f0], a0);
            atomicAdd(&ph[cur * 128 + f1], a1);
            if (l == 0) atomicAdd(&pcnt[cur], cnt);
            a0 = 0.f; a1 = 0.f; cnt = 0; cur = b;
        }
        float2 f = bf2f2(h32[(size_t)r * 64 + l]);
        if (isx) {
            float xn0 = fmaf((f.x - mean0) * inv0, ga0, be0);
            float xn1 = fmaf((f.y - mean1) * inv1, ga1, be1);
            f32x2 o; o.x = xn0; o.y = xn1;
            __builtin_nontemporal_store(o, reinterpret_cast<f32x2*>(&xlocal[(size_t)r * 64 + f0]));
            a0 += xn0; a1 += xn1;
        } else {
            a0 += f.x; a1 += f.y;
        }
        cnt++;
    }
    atomicAdd(&ph[cur * 128 + f0], a0);
    atomicAdd(&ph[cur * 128 + f1], a1);
    if (l == 0) atomicAdd(&pcnt[cur], cnt);
}

// ---------------- tiny final GEMM on pooled sums: pooled = ph @ Wh + n_g*bh  (all f32) ----------------
__global__ __launch_bounds__(256)
void k_out(const float* __restrict__ ph, const int* __restrict__ pcnt,
           const float* __restrict__ Wh, const float* __restrict__ bh,
           float* __restrict__ pooled, int G) {
    int t = blockIdx.x * 256 + threadIdx.x;
    if (t >= G * 64) return;
    int g = t >> 6, j = t & 63;
    float acc = bh[j] * (float)pcnt[g];
    const float* row = ph + g * 128;
#pragma unroll 4
    for (int k = 0; k < 128; ++k) acc = fmaf(row[k], Wh[k * 64 + j], acc);
    pooled[t] = acc;
}

extern "C" void kernel_launch(void* const* d_in, const int* in_sizes, int n_in,
                              void* d_out, int out_size, void* d_ws, size_t ws_size,
                              hipStream_t stream) {
    const float* x_in  = (const float*)d_in[0];
    const float* s_in  = (const float*)d_in[1];
    const float* W1    = (const float*)d_in[2];
    const float* W2    = (const float*)d_in[3];
    const float* gamma = (const float*)d_in[4];
    const float* beta  = (const float*)d_in[5];
    const float* Wg    = (const float*)d_in[6];
    const float* bg    = (const float*)d_in[7];
    const float* Wh    = (const float*)d_in[8];
    const float* bh    = (const float*)d_in[9];
    const int*   ei    = (const int*)d_in[10];
    const int*   batch = (const int*)d_in[11];

    int N = in_sizes[0] / 64;
    int E = in_sizes[10] / 2;
    int L = in_sizes[2] / 8192;
    int G = out_size / 64 - N;

    const int* src = ei;
    const int* dst = ei + E;

    float* pooled = (float*)d_out;
    float* xlocal = pooled + (size_t)G * 64;      // final BN'd x (f32) output

    char* p = (char*)d_ws;
    auto alloc = [&](size_t bytes) { char* r = p; p += (bytes + 255) & ~(size_t)255; return r; };
    ushort* hA   = (ushort*)alloc((size_t)N * 128 * 2);
    ushort* hB   = (ushort*)alloc((size_t)N * 128 * 2);
    float* dinv  = (float*)alloc((size_t)N * 4);
    float* stats = (float*)alloc(128 * 4);
    float* ph    = (float*)alloc((size_t)G * 128 * 4);   // pooled concat partials
    int* pcnt    = (int*)alloc((size_t)G * 4);           // per-graph row counts
    int* rowptr  = (int*)alloc((size_t)(N + 1) * 4);
    int* cnt     = (int*)alloc((size_t)N * 4);           // histogram, then fill cursor
    void* colv   = (void*)alloc((size_t)E * 4);
    int* btot    = (int*)alloc(256 * 4);
    int* boff    = (int*)alloc(256 * 4);
    ushort* W1T  = (ushort*)alloc((size_t)L * 8192 * 2);
    ushort* W2T  = (ushort*)alloc((size_t)L * 4096 * 2);
    ushort* WgT  = (ushort*)alloc((size_t)L * 4096 * 2);

    int NB = (N + 1023) / 1024;
    int nprep = L * 16384;
    int E4 = (E + 3) / 4;
    int gBlk = (N + 63) / 64;

    hipMemsetAsync(cnt, 0, (size_t)N * sizeof(int), stream);
    hipMemsetAsync(ph, 0, (size_t)G * 128 * sizeof(float), stream);
    hipMemsetAsync(pcnt, 0, (size_t)G * sizeof(int), stream);
    hipMemsetAsync(stats, 0, 128 * sizeof(float), stream);
    k_prep<<<(nprep + 255) / 256, 256, 0, stream>>>(W1, W2, Wg, W1T, W2T, WgT, L);
    k_hist<<<(E4 + 255) / 256, 256, 0, stream>>>(dst, cnt, E);
    k_scanA<<<NB, 256, 0, stream>>>(cnt, btot, N);
    k_scanB<<<1, 256, 0, stream>>>(btot, boff, rowptr, NB, N, E);
    k_scanC<<<NB, 256, 0, stream>>>(cnt, boff, rowptr, dinv, N);
    k_pack<<<(N * 16 + 255) / 256, 256, 0, stream>>>(x_in, s_in, hA, N * 16);

    ushort* hin = hA;
    ushort* hout = hB;
    if (N <= 65536) {
        ushort* col = (ushort*)colv;
        k_fill<ushort><<<(E4 + 255) / 256, 256, 0, stream>>>(src, dst, cnt, col, E);
        for (int i = 0; i < L; ++i) {
            k_fused<ushort><<<gBlk, 256, 0, stream>>>((const uint*)hin, dinv, rowptr, col,
                                                      W1T + (size_t)i * 8192, W2T + (size_t)i * 4096,
                                                      WgT + (size_t)i * 4096, bg + (size_t)i * 64,
                                                      hout, N);
            ushort* t = hin; hin = hout; hout = t;
        }
    } else {
        int* col = (int*)colv;
        k_fill<int><<<(E4 + 255) / 256, 256, 0, stream>>>(src, dst, cnt, col, E);
        for (int i = 0; i < L; ++i) {
            k_fused<int><<<gBlk, 256, 0, stream>>>((const uint*)hin, dinv, rowptr, col,
                                                   W1T + (size_t)i * 8192, W2T + (size_t)i * 4096,
                                                   WgT + (size_t)i * 4096, bg + (size_t)i * 64,
                                                   hout, N);
            ushort* t = hin; hin = hout; hout = t;
        }
    }

    // hin now points at the final-layer h
    k_bnstats<<<256, 256, 0, stream>>>(hin, stats, N);
    int nwaves = 2048;
    int rpw = (N + nwaves - 1) / nwaves;
    k_bnpool<<<nwaves / 4, 256, 0, stream>>>((const uint*)hin, stats,
                                             gamma + (size_t)(L - 1) * 64,
                                             beta + (size_t)(L - 1) * 64,
                                             batch, xlocal, ph, pcnt, N, rpw);
    k_out<<<(G * 64 + 255) / 256, 256, 0, stream>>>(ph, pcnt, Wh, bh, pooled, G);
}

// Round 6
// 353.720 us; speedup vs baseline: 1.0916x; 1.0916x over previous
//
#include <hip/hip_runtime.h>
#include <hip/hip_bf16.h>

typedef unsigned int uint;
typedef unsigned short ushort;
typedef __attribute__((ext_vector_type(8))) short bf16x8;
typedef __attribute__((ext_vector_type(4))) float f32x4;
typedef __attribute__((ext_vector_type(2))) float f32x2;
typedef __attribute__((ext_vector_type(4))) int i32x4;
typedef __attribute__((ext_vector_type(4))) float f32x4v;

// ---- bf16 helpers (f32 accumulate everywhere; bf16 only for stored tensors) ----
__device__ __forceinline__ float2 bf2f2(uint p) {
    float2 r;
    r.x = __uint_as_float(p << 16);
    r.y = __uint_as_float(p & 0xffff0000u);
    return r;
}
__device__ __forceinline__ ushort f2bf(float f) {
    uint u = __float_as_uint(f);
    return (ushort)((u + 0x7fffu + ((u >> 16) & 1u)) >> 16);
}
__device__ __forceinline__ uint packbf(float a, float b) {
    return (uint)f2bf(a) | ((uint)f2bf(b) << 16);
}

// ---------------- CSR build ----------------
__global__ void k_hist(const int* __restrict__ dst, int* __restrict__ cnt, int E) {
    int e = (blockIdx.x * 256 + threadIdx.x) * 4;
    if (e + 3 < E) {
        i32x4 d = __builtin_nontemporal_load(reinterpret_cast<const i32x4*>(&dst[e]));
        atomicAdd(&cnt[d.x], 1);
        atomicAdd(&cnt[d.y], 1);
        atomicAdd(&cnt[d.z], 1);
        atomicAdd(&cnt[d.w], 1);
    } else {
        for (int q = 0; q < 4; ++q)
            if (e + q < E) atomicAdd(&cnt[dst[e + q]], 1);
    }
}

__device__ __forceinline__ int block_excl_scan(int tsum, int tid, int* wtot) {
    int lane = tid & 63, w = tid >> 6;
    int incl = tsum;
    for (int off = 1; off < 64; off <<= 1) {
        int t = __shfl_up(incl, off);
        if (lane >= off) incl += t;
    }
    if (lane == 63) wtot[w] = incl;
    __syncthreads();
    int woff = 0;
    if (w > 0) woff = wtot[0];
    if (w > 1) woff += wtot[1];
    if (w > 2) woff += wtot[2];
    return woff + incl - tsum;
}

__global__ __launch_bounds__(256)
void k_scanA(const int* __restrict__ cnt, int* __restrict__ btot, int N) {
    __shared__ int wtot[4];
    int tid = threadIdx.x;
    int base = blockIdx.x * 1024 + tid * 4;
    int s = 0;
    if (base + 3 < N) {
        int4 v = *reinterpret_cast<const int4*>(&cnt[base]);
        s = v.x + v.y + v.z + v.w;
    } else {
#pragma unroll
        for (int q = 0; q < 4; ++q) { int i = base + q; if (i < N) s += cnt[i]; }
    }
    int lane = tid & 63, w = tid >> 6;
    for (int off = 32; off; off >>= 1) s += __shfl_down(s, off);
    if (lane == 0) wtot[w] = s;
    __syncthreads();
    if (tid == 0) btot[blockIdx.x] = wtot[0] + wtot[1] + wtot[2] + wtot[3];
}

__global__ __launch_bounds__(256)
void k_scanB(const int* __restrict__ btot, int* __restrict__ boff,
             int* __restrict__ rowptr, int NB, int N, int E) {
    __shared__ int wtot[4];
    int tid = threadIdx.x;
    int v = (tid < NB) ? btot[tid] : 0;
    int ex = block_excl_scan(v, tid, wtot);
    if (tid < NB) boff[tid] = ex;
    if (tid == 0) rowptr[N] = E;
}

// re-scan chunks + write rowptr/cursor; fused dinv (pre-scan cnt values ARE degrees)
__global__ __launch_bounds__(256)
void k_scanC(int* __restrict__ cnt, const int* __restrict__ boff,
             int* __restrict__ rowptr, float* __restrict__ dinv, int N) {
    __shared__ int wtot[4];
    int tid = threadIdx.x;
    int base = blockIdx.x * 1024 + tid * 4;
    int v0 = 0, v1 = 0, v2 = 0, v3 = 0;
    if (base + 3 < N) {
        int4 v = *reinterpret_cast<const int4*>(&cnt[base]);
        v0 = v.x; v1 = v.y; v2 = v.z; v3 = v.w;
    } else {
        if (base + 0 < N) v0 = cnt[base + 0];
        if (base + 1 < N) v1 = cnt[base + 1];
        if (base + 2 < N) v2 = cnt[base + 2];
        if (base + 3 < N) v3 = cnt[base + 3];
    }
    int tsum = v0 + v1 + v2 + v3;
    int ex = block_excl_scan(tsum, tid, wtot) + boff[blockIdx.x];
    int r0 = ex, r1 = ex + v0, r2 = r1 + v1, r3 = r2 + v2;
    if (base + 0 < N) { rowptr[base + 0] = r0; cnt[base + 0] = r0; dinv[base + 0] = rsqrtf((float)v0 + 1.0f); }
    if (base + 1 < N) { rowptr[base + 1] = r1; cnt[base + 1] = r1; dinv[base + 1] = rsqrtf((float)v1 + 1.0f); }
    if (base + 2 < N) { rowptr[base + 2] = r2; cnt[base + 2] = r2; dinv[base + 2] = rsqrtf((float)v2 + 1.0f); }
    if (base + 3 < N) { rowptr[base + 3] = r3; cnt[base + 3] = r3; dinv[base + 3] = rsqrtf((float)v3 + 1.0f); }
}

template<typename CT>
__global__ void k_fill(const int* __restrict__ src, const int* __restrict__ dst,
                       int* __restrict__ cursor, CT* __restrict__ col, int E) {
    int e = (blockIdx.x * 256 + threadIdx.x) * 4;
    if (e + 3 < E) {
        i32x4 s = __builtin_nontemporal_load(reinterpret_cast<const i32x4*>(&src[e]));
        i32x4 d = __builtin_nontemporal_load(reinterpret_cast<const i32x4*>(&dst[e]));
        col[atomicAdd(&cursor[d.x], 1)] = (CT)s.x;
        col[atomicAdd(&cursor[d.y], 1)] = (CT)s.y;
        col[atomicAdd(&cursor[d.z], 1)] = (CT)s.z;
        col[atomicAdd(&cursor[d.w], 1)] = (CT)s.w;
    } else {
        for (int q = 0; q < 4; ++q)
            if (e + q < E) col[atomicAdd(&cursor[dst[e + q]], 1)] = (CT)src[e + q];
    }
}

// pack h0 = [x | s] as bf16, row stride 128
__global__ void k_pack(const float* __restrict__ xi, const float* __restrict__ si,
                       ushort* __restrict__ h, int n4) {   // n4 = N*16
    int i = blockIdx.x * 256 + threadIdx.x;
    if (i >= n4) return;
    int row = i >> 4, c4 = i & 15;
    f32x4v xv = __builtin_nontemporal_load(reinterpret_cast<const f32x4v*>(&xi[i * 4]));
    f32x4v sv = __builtin_nontemporal_load(reinterpret_cast<const f32x4v*>(&si[i * 4]));
    ushort4 xo, so;
    xo.x = f2bf(xv.x); xo.y = f2bf(xv.y); xo.z = f2bf(xv.z); xo.w = f2bf(xv.w);
    so.x = f2bf(sv.x); so.y = f2bf(sv.y); so.z = f2bf(sv.z); so.w = f2bf(sv.w);
    *reinterpret_cast<ushort4*>(&h[(size_t)row * 128 + c4 * 4]) = xo;
    *reinterpret_cast<ushort4*>(&h[(size_t)row * 128 + 64 + c4 * 4]) = so;
}

// weights: transpose + convert to bf16 once. WT[j][k] = W[k][j]  (Wh stays f32, used by k_out)
__global__ void k_prep(const float* __restrict__ W1, const float* __restrict__ W2,
                       const float* __restrict__ Wg,
                       ushort* __restrict__ W1T, ushort* __restrict__ W2T,
                       ushort* __restrict__ WgT, int L) {
    int i = blockIdx.x * 256 + threadIdx.x;
    int n1 = L * 8192, n2 = L * 4096;
    if (i < n1) {
        int li = i >> 13, r = i & 8191, j = r >> 7, kk = r & 127;
        W1T[i] = f2bf(W1[(size_t)li * 8192 + kk * 64 + j]);
    } else if (i < n1 + n2) {
        int t = i - n1; int li = t >> 12, r = t & 4095, j = r >> 6, kk = r & 63;
        W2T[t] = f2bf(W2[(size_t)li * 4096 + kk * 64 + j]);
    } else if (i < n1 + 2 * n2) {
        int t = i - n1 - n2; int li = t >> 12, r = t & 4095, j = r >> 6, kk = r & 63;
        WgT[t] = f2bf(Wg[(size_t)li * 4096 + kk * 64 + j]);
    }
}

// ---------------- fused gather: GIN agg of h AND dinv-weighted agg of s ----------------
// one wave per dst row (max parallelism); lane l holds feats (2l,2l+1); f32 accum, bf16 out
// col-index loads software-pipelined one group ahead to break the idx->gather chain
template<typename CT>
__global__ __launch_bounds__(256)
void k_agg(const uint* __restrict__ h32, const float* __restrict__ dinv,
           const int* __restrict__ rowptr, const CT* __restrict__ col,
           uint* __restrict__ g32, uint* __restrict__ tb32, int N) {
    int w = threadIdx.x >> 6, l = threadIdx.x & 63;
    int v = blockIdx.x * 4 + w;
    if (v >= N) return;
    float dv = dinv[v];
    float2 hv = bf2f2(h32[(size_t)v * 64 + l]);
    float ax = hv.x, ay = hv.y;
    float dx = dv * hv.x, dy = dv * hv.y;
    int k = rowptr[v], end = rowptr[v + 1];
    int u0 = 0, u1 = 0, u2 = 0, u3 = 0;
    if (k + 3 < end) { u0 = col[k]; u1 = col[k + 1]; u2 = col[k + 2]; u3 = col[k + 3]; }
    for (; k + 7 < end; k += 4) {
        int n0 = col[k + 4], n1 = col[k + 5], n2 = col[k + 6], n3 = col[k + 7];
        float d0 = dinv[u0], d1 = dinv[u1], d2 = dinv[u2], d3 = dinv[u3];
        float2 a = bf2f2(h32[(size_t)u0 * 64 + l]);
        float2 b = bf2f2(h32[(size_t)u1 * 64 + l]);
        float2 c = bf2f2(h32[(size_t)u2 * 64 + l]);
        float2 e = bf2f2(h32[(size_t)u3 * 64 + l]);
        ax += (a.x + b.x) + (c.x + e.x);
        ay += (a.y + b.y) + (c.y + e.y);
        dx = fmaf(d0, a.x, fmaf(d1, b.x, fmaf(d2, c.x, fmaf(d3, e.x, dx))));
        dy = fmaf(d0, a.y, fmaf(d1, b.y, fmaf(d2, c.y, fmaf(d3, e.y, dy))));
        u0 = n0; u1 = n1; u2 = n2; u3 = n3;
    }
    if (k + 3 < end) {
        float d0 = dinv[u0], d1 = dinv[u1], d2 = dinv[u2], d3 = dinv[u3];
        float2 a = bf2f2(h32[(size_t)u0 * 64 + l]);
        float2 b = bf2f2(h32[(size_t)u1 * 64 + l]);
        float2 c = bf2f2(h32[(size_t)u2 * 64 + l]);
        float2 e = bf2f2(h32[(size_t)u3 * 64 + l]);
        ax += (a.x + b.x) + (c.x + e.x);
        ay += (a.y + b.y) + (c.y + e.y);
        dx = fmaf(d0, a.x, fmaf(d1, b.x, fmaf(d2, c.x, fmaf(d3, e.x, dx))));
        dy = fmaf(d0, a.y, fmaf(d1, b.y, fmaf(d2, c.y, fmaf(d3, e.y, dy))));
        k += 4;
    }
    for (; k < end; ++k) {
        int u = col[k];
        float du = dinv[u];
        float2 a = bf2f2(h32[(size_t)u * 64 + l]);
        ax += a.x; ay += a.y;
        dx = fmaf(du, a.x, dx);
        dy = fmaf(du, a.y, dy);
    }
    g32[(size_t)v * 64 + l] = packbf(ax, ay);
    if (l >= 32) tb32[(size_t)v * 32 + (l - 32)] = packbf(dv * dx, dv * dy);
}

// ---------------- MFMA layer: x' = leaky(g@W1)@W2 ; s' = tanh(tb@Wg + bg) ----------------
__global__ __launch_bounds__(256)
void k_layer_mfma(const ushort* __restrict__ g,   // [N][128] bf16
                  const ushort* __restrict__ tb,  // [N][64]  bf16
                  const ushort* __restrict__ W1T, // [64][128]
                  const ushort* __restrict__ W2T, // [64][64]
                  const ushort* __restrict__ WgT, // [64][64]
                  const float* __restrict__ bg,
                  ushort* __restrict__ hout, int N) {
    __shared__ short sT[4][1024];   // per-wave 16x64 bf16 T-tile, XOR-swizzled
    int w = threadIdx.x >> 6, l = threadIdx.x & 63;
    int p = l >> 4, q16 = l & 15;
    int r0 = blockIdx.x * 64 + w * 16;
    int arow = r0 + q16; if (arow >= N) arow = N - 1;   // clamp: no OOB reads
    f32x4 acc1[4] = {};
#pragma unroll
    for (int kt = 0; kt < 4; ++kt) {
        bf16x8 a = *reinterpret_cast<const bf16x8*>(&g[(size_t)arow * 128 + kt * 32 + p * 8]);
#pragma unroll
        for (int jt = 0; jt < 4; ++jt) {
            bf16x8 b = *reinterpret_cast<const bf16x8*>(&W1T[(size_t)(jt * 16 + q16) * 128 + kt * 32 + p * 8]);
            acc1[jt] = __builtin_amdgcn_mfma_f32_16x16x32_bf16(a, b, acc1[jt], 0, 0, 0);
        }
    }
#pragma unroll
    for (int jt = 0; jt < 4; ++jt) {
#pragma unroll
        for (int q = 0; q < 4; ++q) {
            float v = acc1[jt][q];
            v = v > 0.f ? v : 0.01f * v;
            int m = 4 * p + q;
            int c = jt * 16 + q16;
            sT[w][m * 64 + (c ^ ((m & 7) << 3))] = (short)f2bf(v);
        }
    }
    __syncthreads();
    f32x4 acc2[4] = {}, acc3[4] = {};
#pragma unroll
    for (int kt = 0; kt < 2; ++kt) {
        int koff = kt * 32 + p * 8;
        bf16x8 at = *reinterpret_cast<const bf16x8*>(&sT[w][q16 * 64 + (koff ^ ((q16 & 7) << 3))]);
        bf16x8 av = *reinterpret_cast<const bf16x8*>(&tb[(size_t)arow * 64 + koff]);
#pragma unroll
        for (int jt = 0; jt < 4; ++jt) {
            bf16x8 b2 = *reinterpret_cast<const bf16x8*>(&W2T[(size_t)(jt * 16 + q16) * 64 + koff]);
            bf16x8 b3 = *reinterpret_cast<const bf16x8*>(&WgT[(size_t)(jt * 16 + q16) * 64 + koff]);
            acc2[jt] = __builtin_amdgcn_mfma_f32_16x16x32_bf16(at, b2, acc2[jt], 0, 0, 0);
            acc3[jt] = __builtin_amdgcn_mfma_f32_16x16x32_bf16(av, b3, acc3[jt], 0, 0, 0);
        }
    }
#pragma unroll
    for (int jt = 0; jt < 4; ++jt) {
        int c = jt * 16 + q16;
        float bgv = bg[c];
#pragma unroll
        for (int q = 0; q < 4; ++q) {
            int row = r0 + 4 * p + q;
            if (row < N) {
                hout[(size_t)row * 128 + c] = f2bf(acc2[jt][q]);
                hout[(size_t)row * 128 + 64 + c] = f2bf(tanhf(acc3[jt][q] + bgv));
            }
        }
    }
}

// ---------------- BatchNorm stats (final layer only) ----------------
__global__ __launch_bounds__(256)
void k_bnstats(const ushort* __restrict__ h, float* __restrict__ stats, int N) {
    __shared__ float ls[4][64], ls2[4][64];
    int w = threadIdx.x >> 6, j = threadIdx.x & 63;
    float s = 0.f, s2 = 0.f;
    for (int r = blockIdx.x * 4 + w; r < N; r += gridDim.x * 4) {
        float v = __uint_as_float((uint)h[(size_t)r * 128 + j] << 16);
        s += v; s2 += v * v;
    }
    ls[w][j] = s; ls2[w][j] = s2;
    __syncthreads();
    if (w == 0) {
        s = ls[0][j] + ls[1][j] + ls[2][j] + ls[3][j];
        s2 = ls2[0][j] + ls2[1][j] + ls2[2][j] + ls2[3][j];
        atomicAdd(&stats[j], s);
        atomicAdd(&stats[64 + j], s2);
    }
}

// ---------------- fused BN-apply + x_local write + per-graph pooled partials ----------------
__global__ __launch_bounds__(256)
void k_bnpool(const uint* __restrict__ h32, const float* __restrict__ stats,
              const float* __restrict__ gamma, const float* __restrict__ beta,
              const int* __restrict__ batch, float* __restrict__ xlocal,
              float* __restrict__ ph, int* __restrict__ pcnt, int N, int rpw) {
    int wg = blockIdx.x * 4 + (threadIdx.x >> 6);
    int l = threadIdx.x & 63;
    int r = wg * rpw;
    int rend = r + rpw; if (rend > N) rend = N;
    if (r >= rend) return;
    float invN = 1.0f / (float)N;
    bool isx = (l < 32);
    int f0 = 2 * l, f1 = 2 * l + 1;
    float mean0 = 0.f, mean1 = 0.f, inv0 = 1.f, inv1 = 1.f;
    float ga0 = 0.f, ga1 = 0.f, be0 = 0.f, be1 = 0.f;
    if (isx) {
        mean0 = stats[f0] * invN; mean1 = stats[f1] * invN;
        float v0 = stats[64 + f0] * invN - mean0 * mean0;
        float v1 = stats[64 + f1] * invN - mean1 * mean1;
        inv0 = rsqrtf(v0 + 1e-4f); inv1 = rsqrtf(v1 + 1e-4f);
        ga0 = gamma[f0]; ga1 = gamma[f1]; be0 = beta[f0]; be1 = beta[f1];
    }
    int cur = batch[r];
    float a0 = 0.f, a1 = 0.f; int cnt = 0;
    for (; r < rend; ++r) {
        int b = batch[r];
        if (b != cur) {
            atomicAdd(&ph[cur * 128 + f0], a0);
            atomicAdd(&ph[cur * 128 + f1], a1);
            if (l == 0) atomicAdd(&pcnt[cur], cnt);
            a0 = 0.f; a1 = 0.f; cnt = 0; cur = b;
        }
        float2 f = bf2f2(h32[(size_t)r * 64 + l]);
        if (isx) {
            float xn0 = fmaf((f.x - mean0) * inv0, ga0, be0);
            float xn1 = fmaf((f.y - mean1) * inv1, ga1, be1);
            f32x2 o; o.x = xn0; o.y = xn1;
            __builtin_nontemporal_store(o, reinterpret_cast<f32x2*>(&xlocal[(size_t)r * 64 + f0]));
            a0 += xn0; a1 += xn1;
        } else {
            a0 += f.x; a1 += f.y;
        }
        cnt++;
    }
    atomicAdd(&ph[cur * 128 + f0], a0);
    atomicAdd(&ph[cur * 128 + f1], a1);
    if (l == 0) atomicAdd(&pcnt[cur], cnt);
}

// ---------------- tiny final GEMM on pooled sums: pooled = ph @ Wh + n_g*bh  (all f32) ----------------
__global__ __launch_bounds__(256)
void k_out(const float* __restrict__ ph, const int* __restrict__ pcnt,
           const float* __restrict__ Wh, const float* __restrict__ bh,
           float* __restrict__ pooled, int G) {
    int t = blockIdx.x * 256 + threadIdx.x;
    if (t >= G * 64) return;
    int g = t >> 6, j = t & 63;
    float acc = bh[j] * (float)pcnt[g];
    const float* row = ph + g * 128;
#pragma unroll 4
    for (int k = 0; k < 128; ++k) acc = fmaf(row[k], Wh[k * 64 + j], acc);
    pooled[t] = acc;
}

extern "C" void kernel_launch(void* const* d_in, const int* in_sizes, int n_in,
                              void* d_out, int out_size, void* d_ws, size_t ws_size,
                              hipStream_t stream) {
    const float* x_in  = (const float*)d_in[0];
    const float* s_in  = (const float*)d_in[1];
    const float* W1    = (const float*)d_in[2];
    const float* W2    = (const float*)d_in[3];
    const float* gamma = (const float*)d_in[4];
    const float* beta  = (const float*)d_in[5];
    const float* Wg    = (const float*)d_in[6];
    const float* bg    = (const float*)d_in[7];
    const float* Wh    = (const float*)d_in[8];
    const float* bh    = (const float*)d_in[9];
    const int*   ei    = (const int*)d_in[10];
    const int*   batch = (const int*)d_in[11];

    int N = in_sizes[0] / 64;
    int E = in_sizes[10] / 2;
    int L = in_sizes[2] / 8192;
    int G = out_size / 64 - N;

    const int* src = ei;
    const int* dst = ei + E;

    float* pooled = (float*)d_out;
    float* xlocal = pooled + (size_t)G * 64;      // final BN'd x (f32) output
    ushort* tb16  = (ushort*)xlocal;              // tb (bf16 N*64) borrows this slot during layers

    char* p = (char*)d_ws;
    auto alloc = [&](size_t bytes) { char* r = p; p += (bytes + 255) & ~(size_t)255; return r; };
    ushort* h16  = (ushort*)alloc((size_t)N * 128 * 2);
    ushort* g16  = (ushort*)alloc((size_t)N * 128 * 2);
    float* dinv  = (float*)alloc((size_t)N * 4);
    float* stats = (float*)alloc(128 * 4);
    float* ph    = (float*)alloc((size_t)G * 128 * 4);   // pooled concat partials
    int* pcnt    = (int*)alloc((size_t)G * 4);           // per-graph row counts
    int* rowptr  = (int*)alloc((size_t)(N + 1) * 4);
    int* cnt     = (int*)alloc((size_t)N * 4);           // histogram, then fill cursor
    void* colv   = (void*)alloc((size_t)E * 4);
    int* btot    = (int*)alloc(256 * 4);
    int* boff    = (int*)alloc(256 * 4);
    ushort* W1T  = (ushort*)alloc((size_t)L * 8192 * 2);
    ushort* W2T  = (ushort*)alloc((size_t)L * 4096 * 2);
    ushort* WgT  = (ushort*)alloc((size_t)L * 4096 * 2);
    const uint* h32 = (const uint*)h16;
    uint* g32 = (uint*)g16;
    uint* tb32 = (uint*)tb16;

    int NB = (N + 1023) / 1024;
    int nprep = L * 16384;
    int E4 = (E + 3) / 4;
    int gBlk = (N + 63) / 64;

    hipMemsetAsync(cnt, 0, (size_t)N * sizeof(int), stream);
    hipMemsetAsync(ph, 0, (size_t)G * 128 * sizeof(float), stream);
    hipMemsetAsync(pcnt, 0, (size_t)G * sizeof(int), stream);
    hipMemsetAsync(stats, 0, 128 * sizeof(float), stream);
    k_prep<<<(nprep + 255) / 256, 256, 0, stream>>>(W1, W2, Wg, W1T, W2T, WgT, L);
    k_hist<<<(E4 + 255) / 256, 256, 0, stream>>>(dst, cnt, E);
    k_scanA<<<NB, 256, 0, stream>>>(cnt, btot, N);
    k_scanB<<<1, 256, 0, stream>>>(btot, boff, rowptr, NB, N, E);
    k_scanC<<<NB, 256, 0, stream>>>(cnt, boff, rowptr, dinv, N);
    k_pack<<<(N * 16 + 255) / 256, 256, 0, stream>>>(x_in, s_in, h16, N * 16);

    if (N <= 65536) {
        ushort* col = (ushort*)colv;
        k_fill<ushort><<<(E4 + 255) / 256, 256, 0, stream>>>(src, dst, cnt, col, E);
        for (int i = 0; i < L; ++i) {
            k_agg<ushort><<<(N + 3) / 4, 256, 0, stream>>>(h32, dinv, rowptr, col, g32, tb32, N);
            k_layer_mfma<<<gBlk, 256, 0, stream>>>(g16, tb16,
                                                   W1T + (size_t)i * 8192, W2T + (size_t)i * 4096,
                                                   WgT + (size_t)i * 4096, bg + (size_t)i * 64,
                                                   h16, N);
        }
    } else {
        int* col = (int*)colv;
        k_fill<int><<<(E4 + 255) / 256, 256, 0, stream>>>(src, dst, cnt, col, E);
        for (int i = 0; i < L; ++i) {
            k_agg<int><<<(N + 3) / 4, 256, 0, stream>>>(h32, dinv, rowptr, col, g32, tb32, N);
            k_layer_mfma<<<gBlk, 256, 0, stream>>>(g16, tb16,
                                                   W1T + (size_t)i * 8192, W2T + (size_t)i * 4096,
                                                   WgT + (size_t)i * 4096, bg + (size_t)i * 64,
                                                   h16, N);
        }
    }

    k_bnstats<<<256, 256, 0, stream>>>(h16, stats, N);
    int nwaves = 2048;
    int rpw = (N + nwaves - 1) / nwaves;
    k_bnpool<<<nwaves / 4, 256, 0, stream>>>(h32, stats,
                                             gamma + (size_t)(L - 1) * 64,
                                             beta + (size_t)(L - 1) * 64,
                                             batch, xlocal, ph, pcnt, N, rpw);
    k_out<<<(G * 64 + 255) / 256, 256, 0, stream>>>(ph, pcnt, Wh, bh, pooled, G);
}